// Round 7
// baseline (111.681 us; speedup 1.0000x reference)
//
#include <hip/hip_runtime.h>

// qg_flux, round 7: 3 dispatches, 512-thread blocks.
//   - interior blocks: composite relax^2 (13-pt), composite biharmonic Z2
//     (13-pt, removes the Z stage in mega; z1v recomputed free in epilogue),
//     output stores folded into compute loops.
//   - edge blocks: exact staged path (boundary zeroing preserved).

#define N0 513
#define N1 257
#define NB 16
#define NT 512

#define C0F ((float)(1.0 / 4.006103515625))
#define D0F 4.006103515625f
#define C1F ((float)(1.0 / 4.0244140625))
#define H0SQ 3.814697265625e-06f            // h0^2 = 2^-18, exact
#define INV_DX2 262144.0f                   // 2^18
#define CENTER  1048576.0f                  // 4*2^18
#define BIHC    68719476736.0f              // 2^36, exact
#define INV12S  ((float)(262144.0 / 12.0 * 262144.0))  // INV12 * 2^18

// composite relax^2: u = center (stride su), qq = center q (stride sq).
__device__ __forceinline__ float relax2c(const float* u, int su,
                                         const float* qq, int sq) {
  float X = 4.f * u[0]
          + (u[-2 * su] + u[2 * su] + u[-2] + u[2])
          + 2.f * (u[-su - 1] + u[-su + 1] + u[su - 1] + u[su + 1])
          - (qq[-sq] + qq[sq] + qq[-1] + qq[1]);
  return C0F * (C0F * X - qq[0]);
}

// ---------------------------------------------------------------- drelaxR ---
template<bool INT>
__device__ __forceinline__ void drelaxR_body(
    const float* __restrict__ P, const float* __restrict__ Q,
    float* __restrict__ outp, float* __restrict__ q1p,
    int ti, int tj, int ic0, int jc0, size_t base, size_t cbase, int lid,
    float* __restrict__ sIn, float* __restrict__ sQ,
    float* __restrict__ sT, float* __restrict__ sP) {
  const int n = N0;
  for (int t = lid; t < 38 * 38; t += NT) {
    int r = t / 38, c = t - r * 38;
    int gi = ti - 3 + r, gj = tj - 3 + c;
    float v;
    if constexpr (INT) v = P[(size_t)gi * n + gj];
    else v = (gi >= 0 && gi < n && gj >= 0 && gj < n) ? P[(size_t)gi * n + gj] : 0.f;
    sIn[r * 39 + c] = v;
  }
  for (int t = lid; t < 36 * 36; t += NT) {
    int r = t / 36, c = t - r * 36;
    int gi = ti - 2 + r, gj = tj - 2 + c;
    float v;
    if constexpr (INT) v = Q[(size_t)gi * n + gj] * H0SQ;
    else v = (gi >= 0 && gi < n && gj >= 0 && gj < n) ? Q[(size_t)gi * n + gj] * H0SQ : 0.f;
    sQ[r * 37 + c] = v;
  }
  __syncthreads();
  if constexpr (INT) {
    // composite relax^2: sIn(org-3) -> sP(org-1), 34x34; fused global store
    for (int t = lid; t < 34 * 34; t += NT) {
      int r = t / 34, c = t - r * 34;
      float v = relax2c(&sIn[(r + 2) * 39 + c + 2], 39,
                        &sQ[(r + 1) * 37 + c + 1], 37);
      sP[r * 35 + c] = v;
      if (r >= 1 && r <= 32 && c >= 1 && c <= 32)
        outp[base + (size_t)(ti - 1 + r) * n + (tj - 1 + c)] = v;
    }
    __syncthreads();
  } else {
    for (int t = lid; t < 36 * 36; t += NT) {
      int r = t / 36, c = t - r * 36;
      float v = 0.f;
      if ((ti - 2 + r) >= 1 && (ti - 2 + r) < n - 1 && (tj - 2 + c) >= 1 && (tj - 2 + c) < n - 1)
        v = C0F * (sIn[r * 39 + c + 1] + sIn[(r + 2) * 39 + c + 1] +
                   sIn[(r + 1) * 39 + c] + sIn[(r + 1) * 39 + c + 2] - sQ[r * 37 + c]);
      sT[r * 37 + c] = v;
    }
    __syncthreads();
    for (int t = lid; t < 34 * 34; t += NT) {
      int r = t / 34, c = t - r * 34;
      float v = 0.f;
      if ((ti - 1 + r) >= 1 && (ti - 1 + r) < n - 1 && (tj - 1 + c) >= 1 && (tj - 1 + c) < n - 1)
        v = C0F * (sT[r * 37 + c + 1] + sT[(r + 2) * 37 + c + 1] +
                   sT[(r + 1) * 37 + c] + sT[(r + 1) * 37 + c + 2] - sQ[(r + 1) * 37 + c + 1]);
      sP[r * 35 + c] = v;
    }
    __syncthreads();
    int tx = lid & 31, ty = lid >> 5;
    #pragma unroll
    for (int s = 0; s < 2; s++) {
      int yy = ty + 16 * s;
      int i = ti + yy, j = tj + tx;
      if (i < n && j < n)
        outp[base + (size_t)i * n + j] = sP[(yy + 1) * 35 + tx + 1];
    }
  }
  if (lid < 256) {
    int cy = lid >> 4, cx = lid & 15;
    int ic = ic0 + cy, jc = jc0 + cx;
    if constexpr (INT) {
      int r = 2 * cy + 1, c = 2 * cx + 1;
      float v = 4.f * (D0F * sP[r * 35 + c] - sP[(r - 1) * 35 + c] - sP[(r + 1) * 35 + c]
                       - sP[r * 35 + c - 1] - sP[r * 35 + c + 1] + sQ[(r + 1) * 37 + c + 1]);
      q1p[cbase + (size_t)ic * N1 + jc] = v;
    } else {
      if (ic < N1 && jc < N1) {
        float v = 0.f;
        if (ic >= 1 && ic < N1 - 1 && jc >= 1 && jc < N1 - 1) {
          int r = 2 * cy + 1, c = 2 * cx + 1;
          v = 4.f * (D0F * sP[r * 35 + c] - sP[(r - 1) * 35 + c] - sP[(r + 1) * 35 + c]
                     - sP[r * 35 + c - 1] - sP[r * 35 + c + 1] + sQ[(r + 1) * 37 + c + 1]);
        }
        q1p[cbase + (size_t)ic * N1 + jc] = v;
      }
    }
  }
}

__global__ __launch_bounds__(NT) void drelaxR_k(
    const float* __restrict__ psi, const float* __restrict__ Qg,
    float* __restrict__ out, float* __restrict__ q1) {
  __shared__ float sIn[38 * 39], sQ[36 * 37], sT[36 * 37], sP[34 * 35];
  int bx = blockIdx.x, by = blockIdx.y;
  int ti = by * 32, tj = bx * 32;
  size_t base = (size_t)blockIdx.z * (N0 * N0);
  size_t cbase = (size_t)blockIdx.z * (N1 * N1);
  int lid = threadIdx.y * 32 + threadIdx.x;
  bool inter = (bx >= 1 && bx <= 14 && by >= 1 && by <= 14);
  if (inter)
    drelaxR_body<true>(psi + base, Qg + base, out, q1, ti, tj, 16 * by, 16 * bx,
                       base, cbase, lid, sIn, sQ, sT, sP);
  else
    drelaxR_body<false>(psi + base, Qg + base, out, q1, ti, tj, 16 * by, 16 * bx,
                        base, cbase, lid, sIn, sQ, sT, sP);
}

// ------------------------------------------------------- shared coarse prep --
template<bool INT>
__device__ __forceinline__ void coarse_and_v(
    const float* __restrict__ P, const float* __restrict__ Q,
    const float* __restrict__ q1,
    int ti, int tj, int c0i, int c0j, int lid,
    float* __restrict__ bufA, float* __restrict__ bufB,
    float* __restrict__ sq1, float* __restrict__ sp1) {
  const int n = N0;
  for (int t = lid; t < 25 * 25; t += NT) {
    int r = t / 25, c = t - r * 25;
    int ci = c0i - 1 + r, cj = c0j - 1 + c;
    float v;
    if constexpr (INT) v = q1[(size_t)ci * N1 + cj];
    else v = (ci >= 0 && ci < N1 && cj >= 0 && cj < N1) ? q1[(size_t)ci * N1 + cj] : 0.f;
    sq1[r * 26 + c] = v;
  }
  for (int t = lid; t < 40 * 40; t += NT) {
    int r = t / 40, c = t - r * 40;
    int gi = ti - 4 + r, gj = tj - 4 + c;
    float v;
    if constexpr (INT) v = Q[(size_t)gi * n + gj] * H0SQ;
    else v = (gi >= 0 && gi < n && gj >= 0 && gj < n) ? Q[(size_t)gi * n + gj] * H0SQ : 0.f;
    bufB[r * 41 + c] = v;
  }
  __syncthreads();
  for (int t = lid; t < 23 * 23; t += NT) {
    int r = t / 23, c = t - r * 23;
    float v = 0.f;
    if (INT || ((c0i + r) >= 1 && (c0i + r) < N1 - 1 && (c0j + c) >= 1 && (c0j + c) < N1 - 1))
      v = C1F * (-C1F * (sq1[r * 26 + c + 1] + sq1[(r + 2) * 26 + c + 1] +
                         sq1[(r + 1) * 26 + c] + sq1[(r + 1) * 26 + c + 2])
                 - sq1[(r + 1) * 26 + c + 1]);
    sp1[r * 24 + c] = v;
  }
  __syncthreads();
  for (int t = lid; t < 42 * 42; t += NT) {
    int r = t / 42, c = t - r * 42;
    int gi = ti - 5 + r, gj = tj - 5 + c;
    float v = 0.f;
    if (INT || (gi >= 0 && gi < n && gj >= 0 && gj < n)) {
      int r1 = (gi >> 1) - c0i, c1 = (gj >> 1) - c0j;
      float a = sp1[r1 * 24 + c1],       b = sp1[r1 * 24 + c1 + 1];
      float e = sp1[(r1 + 1) * 24 + c1], d = sp1[(r1 + 1) * 24 + c1 + 1];
      float wx = (gj & 1) ? 0.5f : 0.f, wy = (gi & 1) ? 0.5f : 0.f;
      float r0 = a + wx * (b - a), rr = e + wx * (d - e);
      v = P[(size_t)gi * n + gj] + (r0 + wy * (rr - r0));
    }
    bufA[r * 43 + c] = v;
  }
  __syncthreads();
}

// ------------------------------------------------------------------- vleg ---
template<bool INT>
__device__ __forceinline__ void vleg_body(
    const float* __restrict__ P, const float* __restrict__ Q,
    const float* __restrict__ q1, float* __restrict__ outp, float* __restrict__ q1o,
    int ti, int tj, int c0i, int c0j, int ic0, int jc0,
    size_t base, size_t cbase, int lid,
    float* __restrict__ bufA, float* __restrict__ bufB,
    float* __restrict__ bufC, float* __restrict__ bufD) {
  const int n = N0;
  coarse_and_v<INT>(P, Q, q1, ti, tj, c0i, c0j, lid, bufA, bufB, bufD, bufD + 25 * 26);
  if constexpr (INT) {
    for (int t = lid; t < 38 * 38; t += NT) {      // comp1: A(org-5) -> D(org-3)
      int r = t / 38, c = t - r * 38;
      bufD[r * 39 + c] = relax2c(&bufA[(r + 2) * 43 + c + 2], 43,
                                 &bufB[(r + 1) * 41 + c + 1], 41);
    }
    __syncthreads();
    for (int t = lid; t < 34 * 34; t += NT) {      // comp2: D -> C(org-1) + store
      int r = t / 34, c = t - r * 34;
      float v = relax2c(&bufD[(r + 2) * 39 + c + 2], 39,
                        &bufB[(r + 3) * 41 + c + 3], 41);
      bufC[r * 35 + c] = v;
      if (r >= 1 && r <= 32 && c >= 1 && c <= 32)
        outp[base + (size_t)(ti - 1 + r) * n + (tj - 1 + c)] = v;
    }
    __syncthreads();
  } else {
    for (int t = lid; t < 40 * 40; t += NT) {
      int r = t / 40, c = t - r * 40;
      float v = 0.f;
      if ((ti - 4 + r) >= 1 && (ti - 4 + r) < n - 1 && (tj - 4 + c) >= 1 && (tj - 4 + c) < n - 1)
        v = C0F * (bufA[r * 43 + c + 1] + bufA[(r + 2) * 43 + c + 1] +
                   bufA[(r + 1) * 43 + c] + bufA[(r + 1) * 43 + c + 2] - bufB[r * 41 + c]);
      bufC[r * 41 + c] = v;
    }
    __syncthreads();
    for (int t = lid; t < 38 * 38; t += NT) {
      int r = t / 38, c = t - r * 38;
      float v = 0.f;
      if ((ti - 3 + r) >= 1 && (ti - 3 + r) < n - 1 && (tj - 3 + c) >= 1 && (tj - 3 + c) < n - 1)
        v = C0F * (bufC[r * 41 + c + 1] + bufC[(r + 2) * 41 + c + 1] +
                   bufC[(r + 1) * 41 + c] + bufC[(r + 1) * 41 + c + 2] - bufB[(r + 1) * 41 + c + 1]);
      bufD[r * 39 + c] = v;
    }
    __syncthreads();
    for (int t = lid; t < 36 * 36; t += NT) {
      int r = t / 36, c = t - r * 36;
      float v = 0.f;
      if ((ti - 2 + r) >= 1 && (ti - 2 + r) < n - 1 && (tj - 2 + c) >= 1 && (tj - 2 + c) < n - 1)
        v = C0F * (bufD[r * 39 + c + 1] + bufD[(r + 2) * 39 + c + 1] +
                   bufD[(r + 1) * 39 + c] + bufD[(r + 1) * 39 + c + 2] - bufB[(r + 2) * 41 + c + 2]);
      bufA[r * 37 + c] = v;
    }
    __syncthreads();
    for (int t = lid; t < 34 * 34; t += NT) {
      int r = t / 34, c = t - r * 34;
      float v = 0.f;
      if ((ti - 1 + r) >= 1 && (ti - 1 + r) < n - 1 && (tj - 1 + c) >= 1 && (tj - 1 + c) < n - 1)
        v = C0F * (bufA[r * 37 + c + 1] + bufA[(r + 2) * 37 + c + 1] +
                   bufA[(r + 1) * 37 + c] + bufA[(r + 1) * 37 + c + 2] - bufB[(r + 3) * 41 + c + 3]);
      bufC[r * 35 + c] = v;
    }
    __syncthreads();
    int tx = lid & 31, ty = lid >> 5;
    #pragma unroll
    for (int s = 0; s < 2; s++) {
      int yy = ty + 16 * s;
      int i = ti + yy, j = tj + tx;
      if (i < n && j < n)
        outp[base + (size_t)i * n + j] = bufC[(yy + 1) * 35 + tx + 1];
    }
  }
  if (lid < 256) {
    int cy = lid >> 4, cx = lid & 15;
    int ic = ic0 + cy, jc = jc0 + cx;
    if constexpr (INT) {
      int r = 2 * cy + 1, c = 2 * cx + 1;
      float v = 4.f * (D0F * bufC[r * 35 + c] - bufC[(r - 1) * 35 + c] - bufC[(r + 1) * 35 + c]
                       - bufC[r * 35 + c - 1] - bufC[r * 35 + c + 1]
                       + bufB[(2 * cy + 4) * 41 + 2 * cx + 4]);
      q1o[cbase + (size_t)ic * N1 + jc] = v;
    } else {
      if (ic < N1 && jc < N1) {
        float v = 0.f;
        if (ic >= 1 && ic < N1 - 1 && jc >= 1 && jc < N1 - 1) {
          int r = 2 * cy + 1, c = 2 * cx + 1;
          v = 4.f * (D0F * bufC[r * 35 + c] - bufC[(r - 1) * 35 + c] - bufC[(r + 1) * 35 + c]
                     - bufC[r * 35 + c - 1] - bufC[r * 35 + c + 1]
                     + bufB[(2 * cy + 4) * 41 + 2 * cx + 4]);
        }
        q1o[cbase + (size_t)ic * N1 + jc] = v;
      }
    }
  }
}

__global__ __launch_bounds__(NT) void vleg_k(
    const float* __restrict__ psi, const float* __restrict__ Qg,
    const float* __restrict__ q1g, float* __restrict__ out, float* __restrict__ q1o) {
  __shared__ float bufA[42 * 43];
  __shared__ float bufB[40 * 41];
  __shared__ float bufC[40 * 41];
  __shared__ float bufD[38 * 39];
  int bx = blockIdx.x, by = blockIdx.y;
  int ti = by * 32, tj = bx * 32;
  int c0i = 16 * by - 3, c0j = 16 * bx - 3;
  size_t base = (size_t)blockIdx.z * (N0 * N0);
  size_t cbase = (size_t)blockIdx.z * (N1 * N1);
  const float* q1 = q1g + cbase;
  int lid = threadIdx.y * 32 + threadIdx.x;
  bool inter = (bx >= 1 && bx <= 14 && by >= 1 && by <= 14);
  if (inter)
    vleg_body<true>(psi + base, Qg + base, q1, out, q1o, ti, tj, c0i, c0j,
                    16 * by, 16 * bx, base, cbase, lid, bufA, bufB, bufC, bufD);
  else
    vleg_body<false>(psi + base, Qg + base, q1, out, q1o, ti, tj, c0i, c0j,
                     16 * by, 16 * bx, base, cbase, lid, bufA, bufB, bufC, bufD);
}

// ------------------------------------------------------------------- mega ---
template<bool INT>
__device__ __forceinline__ void mega_body(
    const float* __restrict__ P, const float* __restrict__ Q,
    const float* __restrict__ q1, const float* __restrict__ CT,
    float* __restrict__ psi_out, float* __restrict__ qf_out,
    int ti, int tj, int c0i, int c0j, size_t base, int lid,
    float* __restrict__ bufA, float* __restrict__ bufB,
    float* __restrict__ bufC, float* __restrict__ bufD) {
  const int n = N0;
  coarse_and_v<INT>(P, Q, q1, ti, tj, c0i, c0j, lid, bufA, bufB, bufD, bufD + 25 * 26);
  if constexpr (INT) {
    // composite relax^2: bufA(org-5) -> bufD (sP, 38x38, org-3)
    for (int t = lid; t < 38 * 38; t += NT) {
      int r = t / 38, c = t - r * 38;
      bufD[r * 39 + c] = relax2c(&bufA[(r + 2) * 43 + c + 2], 43,
                                 &bufB[(r + 1) * 41 + c + 1], 41);
    }
    __syncthreads();
    // composite biharmonic: Z2 = 2^36*(20C + A2 + 2D - 8A1) on sP -> bufC(org-1)
    for (int t = lid; t < 34 * 34; t += NT) {
      int r = t / 34, c = t - r * 34;
      const float* u = &bufD[(r + 2) * 39 + (c + 2)];
      float a1 = u[-39] + u[39] + u[-1] + u[1];
      float dg = u[-40] + u[-38] + u[38] + u[40];
      float a2 = u[-78] + u[78] + u[-2] + u[2];
      bufC[r * 35 + c] = BIHC * (20.f * u[0] + a2 + 2.f * dg - 8.f * a1);
    }
    __syncthreads();
  } else {
    for (int t = lid; t < 40 * 40; t += NT) {
      int r = t / 40, c = t - r * 40;
      float v = 0.f;
      if ((ti - 4 + r) >= 1 && (ti - 4 + r) < n - 1 && (tj - 4 + c) >= 1 && (tj - 4 + c) < n - 1)
        v = C0F * (bufA[r * 43 + c + 1] + bufA[(r + 2) * 43 + c + 1] +
                   bufA[(r + 1) * 43 + c] + bufA[(r + 1) * 43 + c + 2] - bufB[r * 41 + c]);
      bufC[r * 41 + c] = v;
    }
    __syncthreads();
    for (int t = lid; t < 38 * 38; t += NT) {
      int r = t / 38, c = t - r * 38;
      float v = 0.f;
      if ((ti - 3 + r) >= 1 && (ti - 3 + r) < n - 1 && (tj - 3 + c) >= 1 && (tj - 3 + c) < n - 1)
        v = C0F * (bufC[r * 41 + c + 1] + bufC[(r + 2) * 41 + c + 1] +
                   bufC[(r + 1) * 41 + c] + bufC[(r + 1) * 41 + c + 2] - bufB[(r + 1) * 41 + c + 1]);
      bufD[r * 39 + c] = v;
    }
    __syncthreads();
    for (int t = lid; t < 36 * 36; t += NT) {     // Z -> bufA stride37 (org-2)
      int r = t / 36, c = t - r * 36;
      float v = 0.f;
      if ((ti - 2 + r) >= 1 && (ti - 2 + r) < n - 1 && (tj - 2 + c) >= 1 && (tj - 2 + c) < n - 1)
        v = (bufD[r * 39 + c + 1] + bufD[(r + 2) * 39 + c + 1] +
             bufD[(r + 1) * 39 + c] + bufD[(r + 1) * 39 + c + 2]) * INV_DX2
            - bufD[(r + 1) * 39 + c + 1] * CENTER;
      bufA[r * 37 + c] = v;
    }
    __syncthreads();
    for (int t = lid; t < 34 * 34; t += NT) {     // Z2 -> bufC stride35 (org-1)
      int r = t / 34, c = t - r * 34;
      float v = 0.f;
      if ((ti - 1 + r) >= 1 && (ti - 1 + r) < n - 1 && (tj - 1 + c) >= 1 && (tj - 1 + c) < n - 1)
        v = (bufA[r * 37 + c + 1] + bufA[(r + 2) * 37 + c + 1] +
             bufA[(r + 1) * 37 + c] + bufA[(r + 1) * 37 + c + 2]) * INV_DX2
            - bufA[(r + 1) * 37 + c + 1] * CENTER;
      bufC[r * 35 + c] = v;
    }
    __syncthreads();
  }
  int tx = lid & 31, ty = lid >> 5;
  #pragma unroll
  for (int s = 0; s < 2; s++) {
    int yy = ty + 16 * s;
    int i = ti + yy, j = tj + tx;
    if (!INT && (i >= n || j >= n)) continue;
    size_t idx = base + (size_t)i * n + j;
    int pr = yy + 3, pc = tx + 3;
    float Acen = bufD[pr * 39 + pc];
    psi_out[idx] = Acen;
    float qv = 0.f;
    if (INT || (i >= 1 && i < n - 1 && j >= 1 && j < n - 1)) {
      float Amm = bufD[(pr - 1) * 39 + pc - 1], Am0 = bufD[(pr - 1) * 39 + pc],
            Amp = bufD[(pr - 1) * 39 + pc + 1];
      float A0m = bufD[pr * 39 + pc - 1], A0p = bufD[pr * 39 + pc + 1];
      float Apm = bufD[(pr + 1) * 39 + pc - 1], Ap0 = bufD[(pr + 1) * 39 + pc],
            App = bufD[(pr + 1) * 39 + pc + 1];
      float z1v;
      if constexpr (INT)
        z1v = (Am0 + Ap0 + A0m + A0p) * INV_DX2 - Acen * CENTER;
      else
        z1v = bufA[(yy + 2) * 37 + tx + 2];
      int r2 = yy + 1, c2 = tx + 1;
      float z2v = bufC[r2 * 35 + c2];
      float z4 = (bufC[r2 * 35 + c2 - 1] + bufC[r2 * 35 + c2 + 1] +
                  bufC[(r2 - 1) * 35 + c2] + bufC[(r2 + 1) * 35 + c2]) * INV_DX2
                 - z2v * CENTER;
      int qr = yy + 4, qc = tx + 4;
      float J = (A0m - Am0) * bufB[(qr - 1) * 41 + qc - 1]
              + (Amm + A0m - Amp - A0p) * bufB[(qr - 1) * 41 + qc]
              + (Am0 - A0p) * bufB[(qr - 1) * 41 + qc + 1]
              + (Apm + Ap0 - Amm - Am0) * bufB[qr * 41 + qc - 1]
              + (Am0 + Amp - Ap0 - App) * bufB[qr * 41 + qc + 1]
              + (Ap0 - A0m) * bufB[(qr + 1) * 41 + qc - 1]
              + (A0p + App - A0m - Apm) * bufB[(qr + 1) * 41 + qc]
              + (A0p - Ap0) * bufB[(qr + 1) * 41 + qc + 1];
      J *= INV12S;
      float ct = CT[(size_t)i * n + j];
      qv = -J - 1e-6f * z1v + 1e-8f * z2v - 2e-11f * z4 + ct - 256.0f * (A0p - A0m);
    }
    qf_out[idx] = qv;
  }
}

__global__ __launch_bounds__(NT) void mega_k(
    const float* __restrict__ psi, const float* __restrict__ Qg,
    const float* __restrict__ q1g, const float* __restrict__ CT,
    float* __restrict__ psi_out, float* __restrict__ qf_out) {
  __shared__ float bufA[42 * 43];
  __shared__ float bufB[40 * 41];
  __shared__ float bufC[40 * 41];
  __shared__ float bufD[38 * 39];
  int bx = blockIdx.x, by = blockIdx.y;
  int ti = by * 32, tj = bx * 32;
  int c0i = 16 * by - 3, c0j = 16 * bx - 3;
  size_t base = (size_t)blockIdx.z * (N0 * N0);
  const float* q1 = q1g + (size_t)blockIdx.z * (N1 * N1);
  int lid = threadIdx.y * 32 + threadIdx.x;
  bool inter = (bx >= 1 && bx <= 14 && by >= 1 && by <= 14);
  if (inter)
    mega_body<true>(psi + base, Qg + base, q1, CT, psi_out, qf_out,
                    ti, tj, c0i, c0j, base, lid, bufA, bufB, bufC, bufD);
  else
    mega_body<false>(psi + base, Qg + base, q1, CT, psi_out, qf_out,
                     ti, tj, c0i, c0j, base, lid, bufA, bufB, bufC, bufD);
}

extern "C" void kernel_launch(void* const* d_in, const int* in_sizes, int n_in,
                              void* d_out, int out_size, void* d_ws, size_t ws_size,
                              hipStream_t stream) {
  const float* PSIG = (const float*)d_in[1];
  const float* Q    = (const float*)d_in[2];
  const float* CT   = (const float*)d_in[3];

  float* ws = (float*)d_ws;
  size_t f0 = (size_t)NB * N0 * N0;
  size_t f1 = (size_t)NB * N1 * N1;
  float* pA  = ws;
  float* pB  = pA + f0;
  float* q1a = pB + f0;
  float* q1b = q1a + f1;

  dim3 blk(32, 16, 1), grd(17, 17, NB);

  drelaxR_k<<<grd, blk, 0, stream>>>(PSIG, Q, pA, q1a);      // cycle-1 down
  vleg_k<<<grd, blk, 0, stream>>>(pA, Q, q1a, pB, q1b);      // c1 up + c2 down
  float* psi_out = (float*)d_out;
  float* qf_out  = psi_out + f0;
  mega_k<<<grd, blk, 0, stream>>>(pB, Q, q1b, CT, psi_out, qf_out);  // c2 up + flux
}

// Round 8
// 109.457 us; speedup vs baseline: 1.0203x; 1.0203x over previous
//
#include <hip/hip_runtime.h>

// qg_flux, round 8: 3 dispatches, 512-thread blocks, ALL-STAGED sweeps.
// r7 post-mortem: composite stencils INCREASE LDS traffic (staged intermediates
// amortize reads 5x). Reverted to staged 5-pt sweeps everywhere; kept NT=512,
// interior/edge template, fused output stores, free z1v, scaled-q J.

#define N0 513
#define N1 257
#define NB 16
#define NT 512

#define C0F ((float)(1.0 / 4.006103515625))
#define D0F 4.006103515625f
#define C1F ((float)(1.0 / 4.0244140625))
#define H0SQ 3.814697265625e-06f            // h0^2 = 2^-18, exact
#define INV_DX2 262144.0f                   // 2^18
#define CENTER  1048576.0f                  // 4*2^18
#define INV12S  ((float)(262144.0 / 12.0 * 262144.0))  // INV12 * 2^18

// ---------------------------------------------------------------- drelaxR ---
// psi' = relax^2(psi, q0) staged; fused rescale -> q1.
template<bool INT>
__device__ __forceinline__ void drelaxR_body(
    const float* __restrict__ P, const float* __restrict__ Q,
    float* __restrict__ outp, float* __restrict__ q1p,
    int ti, int tj, int ic0, int jc0, size_t base, size_t cbase, int lid,
    float* __restrict__ sIn, float* __restrict__ sQ,
    float* __restrict__ sT, float* __restrict__ sP) {
  const int n = N0;
  for (int t = lid; t < 38 * 38; t += NT) {
    int r = t / 38, c = t - r * 38;
    int gi = ti - 3 + r, gj = tj - 3 + c;
    float v;
    if constexpr (INT) v = P[(size_t)gi * n + gj];
    else v = (gi >= 0 && gi < n && gj >= 0 && gj < n) ? P[(size_t)gi * n + gj] : 0.f;
    sIn[r * 39 + c] = v;
  }
  for (int t = lid; t < 36 * 36; t += NT) {
    int r = t / 36, c = t - r * 36;
    int gi = ti - 2 + r, gj = tj - 2 + c;
    float v;
    if constexpr (INT) v = Q[(size_t)gi * n + gj] * H0SQ;
    else v = (gi >= 0 && gi < n && gj >= 0 && gj < n) ? Q[(size_t)gi * n + gj] * H0SQ : 0.f;
    sQ[r * 37 + c] = v;
  }
  __syncthreads();
  // s1: 36x36 (org-2)
  for (int t = lid; t < 36 * 36; t += NT) {
    int r = t / 36, c = t - r * 36;
    float v = 0.f;
    if (INT || ((ti - 2 + r) >= 1 && (ti - 2 + r) < n - 1 && (tj - 2 + c) >= 1 && (tj - 2 + c) < n - 1))
      v = C0F * (sIn[r * 39 + c + 1] + sIn[(r + 2) * 39 + c + 1] +
                 sIn[(r + 1) * 39 + c] + sIn[(r + 1) * 39 + c + 2] - sQ[r * 37 + c]);
    sT[r * 37 + c] = v;
  }
  __syncthreads();
  // s2: 34x34 (org-1) -> sP (aliases sIn), fused global store
  for (int t = lid; t < 34 * 34; t += NT) {
    int r = t / 34, c = t - r * 34;
    float v = 0.f;
    if (INT || ((ti - 1 + r) >= 1 && (ti - 1 + r) < n - 1 && (tj - 1 + c) >= 1 && (tj - 1 + c) < n - 1))
      v = C0F * (sT[r * 37 + c + 1] + sT[(r + 2) * 37 + c + 1] +
                 sT[(r + 1) * 37 + c] + sT[(r + 1) * 37 + c + 2] - sQ[(r + 1) * 37 + c + 1]);
    sP[r * 35 + c] = v;
    if (r >= 1 && r <= 32 && c >= 1 && c <= 32 &&
        (INT || ((ti - 1 + r) < n && (tj - 1 + c) < n)))
      outp[base + (size_t)(ti - 1 + r) * n + (tj - 1 + c)] = v;
  }
  __syncthreads();
  if (lid < 256) {
    int cy = lid >> 4, cx = lid & 15;
    int ic = ic0 + cy, jc = jc0 + cx;
    if (INT || (ic < N1 && jc < N1)) {
      float v = 0.f;
      if (INT || (ic >= 1 && ic < N1 - 1 && jc >= 1 && jc < N1 - 1)) {
        int r = 2 * cy + 1, c = 2 * cx + 1;
        v = 4.f * (D0F * sP[r * 35 + c] - sP[(r - 1) * 35 + c] - sP[(r + 1) * 35 + c]
                   - sP[r * 35 + c - 1] - sP[r * 35 + c + 1] + sQ[(r + 1) * 37 + c + 1]);
      }
      q1p[cbase + (size_t)ic * N1 + jc] = v;
    }
  }
}

__global__ __launch_bounds__(NT) void drelaxR_k(
    const float* __restrict__ psi, const float* __restrict__ Qg,
    float* __restrict__ out, float* __restrict__ q1) {
  __shared__ float smem[38 * 39 + 36 * 37 + 36 * 37];
  float* sIn = smem;
  float* sQ  = smem + 38 * 39;
  float* sT  = sQ + 36 * 37;
  float* sP  = smem;               // alias sIn (dead after s1)
  int bx = blockIdx.x, by = blockIdx.y;
  int ti = by * 32, tj = bx * 32;
  size_t base = (size_t)blockIdx.z * (N0 * N0);
  size_t cbase = (size_t)blockIdx.z * (N1 * N1);
  int lid = threadIdx.y * 32 + threadIdx.x;
  bool inter = (bx >= 1 && bx <= 14 && by >= 1 && by <= 14);
  if (inter)
    drelaxR_body<true>(psi + base, Qg + base, out, q1, ti, tj, 16 * by, 16 * bx,
                       base, cbase, lid, sIn, sQ, sT, sP);
  else
    drelaxR_body<false>(psi + base, Qg + base, out, q1, ti, tj, 16 * by, 16 * bx,
                        base, cbase, lid, sIn, sQ, sT, sP);
}

// ------------------------------------------------------- shared coarse prep --
// sq1(25x25@c0-1)+q0(40x40@ti-4, scaled) staged; p1(23x23@c0); v=P+up(p1)
// (42x42@ti-5) into bufA.
template<bool INT>
__device__ __forceinline__ void coarse_and_v(
    const float* __restrict__ P, const float* __restrict__ Q,
    const float* __restrict__ q1,
    int ti, int tj, int c0i, int c0j, int lid,
    float* __restrict__ bufA, float* __restrict__ bufB,
    float* __restrict__ sq1, float* __restrict__ sp1) {
  const int n = N0;
  for (int t = lid; t < 25 * 25; t += NT) {
    int r = t / 25, c = t - r * 25;
    int ci = c0i - 1 + r, cj = c0j - 1 + c;
    float v;
    if constexpr (INT) v = q1[(size_t)ci * N1 + cj];
    else v = (ci >= 0 && ci < N1 && cj >= 0 && cj < N1) ? q1[(size_t)ci * N1 + cj] : 0.f;
    sq1[r * 26 + c] = v;
  }
  for (int t = lid; t < 40 * 40; t += NT) {
    int r = t / 40, c = t - r * 40;
    int gi = ti - 4 + r, gj = tj - 4 + c;
    float v;
    if constexpr (INT) v = Q[(size_t)gi * n + gj] * H0SQ;
    else v = (gi >= 0 && gi < n && gj >= 0 && gj < n) ? Q[(size_t)gi * n + gj] * H0SQ : 0.f;
    bufB[r * 41 + c] = v;
  }
  __syncthreads();
  for (int t = lid; t < 23 * 23; t += NT) {
    int r = t / 23, c = t - r * 23;
    float v = 0.f;
    if (INT || ((c0i + r) >= 1 && (c0i + r) < N1 - 1 && (c0j + c) >= 1 && (c0j + c) < N1 - 1))
      v = C1F * (-C1F * (sq1[r * 26 + c + 1] + sq1[(r + 2) * 26 + c + 1] +
                         sq1[(r + 1) * 26 + c] + sq1[(r + 1) * 26 + c + 2])
                 - sq1[(r + 1) * 26 + c + 1]);
    sp1[r * 24 + c] = v;
  }
  __syncthreads();
  for (int t = lid; t < 42 * 42; t += NT) {
    int r = t / 42, c = t - r * 42;
    int gi = ti - 5 + r, gj = tj - 5 + c;
    float v = 0.f;
    if (INT || (gi >= 0 && gi < n && gj >= 0 && gj < n)) {
      int r1 = (gi >> 1) - c0i, c1 = (gj >> 1) - c0j;
      float a = sp1[r1 * 24 + c1],       b = sp1[r1 * 24 + c1 + 1];
      float e = sp1[(r1 + 1) * 24 + c1], d = sp1[(r1 + 1) * 24 + c1 + 1];
      float wx = (gj & 1) ? 0.5f : 0.f, wy = (gi & 1) ? 0.5f : 0.f;
      float r0 = a + wx * (b - a), rr = e + wx * (d - e);
      v = P[(size_t)gi * n + gj] + (r0 + wy * (rr - r0));
    }
    bufA[r * 43 + c] = v;
  }
  __syncthreads();
}

// ------------------------------------------------------------------- vleg ---
// relax^4(pA + up(p1)) staged + rescale. Aliasing:
//   A: v(43, org-5) -> s3(37, org-2);  B: q0(41, org-4)
//   C: s1(41, org-4) -> s4(35, org-1); D: coarse -> s2(39, org-3)
template<bool INT>
__device__ __forceinline__ void vleg_body(
    const float* __restrict__ P, const float* __restrict__ Q,
    const float* __restrict__ q1, float* __restrict__ outp, float* __restrict__ q1o,
    int ti, int tj, int c0i, int c0j, int ic0, int jc0,
    size_t base, size_t cbase, int lid,
    float* __restrict__ bufA, float* __restrict__ bufB,
    float* __restrict__ bufC, float* __restrict__ bufD) {
  const int n = N0;
  coarse_and_v<INT>(P, Q, q1, ti, tj, c0i, c0j, lid, bufA, bufB, bufD, bufD + 25 * 26);
  for (int t = lid; t < 40 * 40; t += NT) {   // s1 (org-4)
    int r = t / 40, c = t - r * 40;
    float v = 0.f;
    if (INT || ((ti - 4 + r) >= 1 && (ti - 4 + r) < n - 1 && (tj - 4 + c) >= 1 && (tj - 4 + c) < n - 1))
      v = C0F * (bufA[r * 43 + c + 1] + bufA[(r + 2) * 43 + c + 1] +
                 bufA[(r + 1) * 43 + c] + bufA[(r + 1) * 43 + c + 2] - bufB[r * 41 + c]);
    bufC[r * 41 + c] = v;
  }
  __syncthreads();
  for (int t = lid; t < 38 * 38; t += NT) {   // s2 (org-3); coarse dead
    int r = t / 38, c = t - r * 38;
    float v = 0.f;
    if (INT || ((ti - 3 + r) >= 1 && (ti - 3 + r) < n - 1 && (tj - 3 + c) >= 1 && (tj - 3 + c) < n - 1))
      v = C0F * (bufC[r * 41 + c + 1] + bufC[(r + 2) * 41 + c + 1] +
                 bufC[(r + 1) * 41 + c] + bufC[(r + 1) * 41 + c + 2] - bufB[(r + 1) * 41 + c + 1]);
    bufD[r * 39 + c] = v;
  }
  __syncthreads();
  for (int t = lid; t < 36 * 36; t += NT) {   // s3 (org-2); v dead
    int r = t / 36, c = t - r * 36;
    float v = 0.f;
    if (INT || ((ti - 2 + r) >= 1 && (ti - 2 + r) < n - 1 && (tj - 2 + c) >= 1 && (tj - 2 + c) < n - 1))
      v = C0F * (bufD[r * 39 + c + 1] + bufD[(r + 2) * 39 + c + 1] +
                 bufD[(r + 1) * 39 + c] + bufD[(r + 1) * 39 + c + 2] - bufB[(r + 2) * 41 + c + 2]);
    bufA[r * 37 + c] = v;
  }
  __syncthreads();
  for (int t = lid; t < 34 * 34; t += NT) {   // s4 (org-1); s1 dead; fused store
    int r = t / 34, c = t - r * 34;
    float v = 0.f;
    if (INT || ((ti - 1 + r) >= 1 && (ti - 1 + r) < n - 1 && (tj - 1 + c) >= 1 && (tj - 1 + c) < n - 1))
      v = C0F * (bufA[r * 37 + c + 1] + bufA[(r + 2) * 37 + c + 1] +
                 bufA[(r + 1) * 37 + c] + bufA[(r + 1) * 37 + c + 2] - bufB[(r + 3) * 41 + c + 3]);
    bufC[r * 35 + c] = v;
    if (r >= 1 && r <= 32 && c >= 1 && c <= 32 &&
        (INT || ((ti - 1 + r) < n && (tj - 1 + c) < n)))
      outp[base + (size_t)(ti - 1 + r) * n + (tj - 1 + c)] = v;
  }
  __syncthreads();
  if (lid < 256) {
    int cy = lid >> 4, cx = lid & 15;
    int ic = ic0 + cy, jc = jc0 + cx;
    if (INT || (ic < N1 && jc < N1)) {
      float v = 0.f;
      if (INT || (ic >= 1 && ic < N1 - 1 && jc >= 1 && jc < N1 - 1)) {
        int r = 2 * cy + 1, c = 2 * cx + 1;
        v = 4.f * (D0F * bufC[r * 35 + c] - bufC[(r - 1) * 35 + c] - bufC[(r + 1) * 35 + c]
                   - bufC[r * 35 + c - 1] - bufC[r * 35 + c + 1]
                   + bufB[(2 * cy + 4) * 41 + 2 * cx + 4]);
      }
      q1o[cbase + (size_t)ic * N1 + jc] = v;
    }
  }
}

__global__ __launch_bounds__(NT) void vleg_k(
    const float* __restrict__ psi, const float* __restrict__ Qg,
    const float* __restrict__ q1g, float* __restrict__ out, float* __restrict__ q1o) {
  __shared__ float bufA[42 * 43];
  __shared__ float bufB[40 * 41];
  __shared__ float bufC[40 * 41];
  __shared__ float bufD[38 * 39];
  int bx = blockIdx.x, by = blockIdx.y;
  int ti = by * 32, tj = bx * 32;
  int c0i = 16 * by - 3, c0j = 16 * bx - 3;
  size_t base = (size_t)blockIdx.z * (N0 * N0);
  size_t cbase = (size_t)blockIdx.z * (N1 * N1);
  const float* q1 = q1g + cbase;
  int lid = threadIdx.y * 32 + threadIdx.x;
  bool inter = (bx >= 1 && bx <= 14 && by >= 1 && by <= 14);
  if (inter)
    vleg_body<true>(psi + base, Qg + base, q1, out, q1o, ti, tj, c0i, c0j,
                    16 * by, 16 * bx, base, cbase, lid, bufA, bufB, bufC, bufD);
  else
    vleg_body<false>(psi + base, Qg + base, q1, out, q1o, ti, tj, c0i, c0j,
                     16 * by, 16 * bx, base, cbase, lid, bufA, bufB, bufC, bufD);
}

// ------------------------------------------------------------------- mega ---
// relax^2(pB + up(p1)) staged + Z + Z2 staged + flux epilogue.
template<bool INT>
__device__ __forceinline__ void mega_body(
    const float* __restrict__ P, const float* __restrict__ Q,
    const float* __restrict__ q1, const float* __restrict__ CT,
    float* __restrict__ psi_out, float* __restrict__ qf_out,
    int ti, int tj, int c0i, int c0j, size_t base, int lid,
    float* __restrict__ bufA, float* __restrict__ bufB,
    float* __restrict__ bufC, float* __restrict__ bufD) {
  const int n = N0;
  coarse_and_v<INT>(P, Q, q1, ti, tj, c0i, c0j, lid, bufA, bufB, bufD, bufD + 25 * 26);
  for (int t = lid; t < 40 * 40; t += NT) {   // s1 (org-4)
    int r = t / 40, c = t - r * 40;
    float v = 0.f;
    if (INT || ((ti - 4 + r) >= 1 && (ti - 4 + r) < n - 1 && (tj - 4 + c) >= 1 && (tj - 4 + c) < n - 1))
      v = C0F * (bufA[r * 43 + c + 1] + bufA[(r + 2) * 43 + c + 1] +
                 bufA[(r + 1) * 43 + c] + bufA[(r + 1) * 43 + c + 2] - bufB[r * 41 + c]);
    bufC[r * 41 + c] = v;
  }
  __syncthreads();
  for (int t = lid; t < 38 * 38; t += NT) {   // s2 -> sP (org-3)
    int r = t / 38, c = t - r * 38;
    float v = 0.f;
    if (INT || ((ti - 3 + r) >= 1 && (ti - 3 + r) < n - 1 && (tj - 3 + c) >= 1 && (tj - 3 + c) < n - 1))
      v = C0F * (bufC[r * 41 + c + 1] + bufC[(r + 2) * 41 + c + 1] +
                 bufC[(r + 1) * 41 + c] + bufC[(r + 1) * 41 + c + 2] - bufB[(r + 1) * 41 + c + 1]);
    bufD[r * 39 + c] = v;
  }
  __syncthreads();
  for (int t = lid; t < 36 * 36; t += NT) {   // Z (org-2); v dead
    int r = t / 36, c = t - r * 36;
    float v = 0.f;
    if (INT || ((ti - 2 + r) >= 1 && (ti - 2 + r) < n - 1 && (tj - 2 + c) >= 1 && (tj - 2 + c) < n - 1))
      v = (bufD[r * 39 + c + 1] + bufD[(r + 2) * 39 + c + 1] +
           bufD[(r + 1) * 39 + c] + bufD[(r + 1) * 39 + c + 2]) * INV_DX2
          - bufD[(r + 1) * 39 + c + 1] * CENTER;
    bufA[r * 37 + c] = v;
  }
  __syncthreads();
  for (int t = lid; t < 34 * 34; t += NT) {   // Z2 (org-1); s1 dead
    int r = t / 34, c = t - r * 34;
    float v = 0.f;
    if (INT || ((ti - 1 + r) >= 1 && (ti - 1 + r) < n - 1 && (tj - 1 + c) >= 1 && (tj - 1 + c) < n - 1))
      v = (bufA[r * 37 + c + 1] + bufA[(r + 2) * 37 + c + 1] +
           bufA[(r + 1) * 37 + c] + bufA[(r + 1) * 37 + c + 2]) * INV_DX2
          - bufA[(r + 1) * 37 + c + 1] * CENTER;
    bufC[r * 35 + c] = v;
  }
  __syncthreads();
  int tx = lid & 31, ty = lid >> 5;
  #pragma unroll
  for (int s = 0; s < 2; s++) {
    int yy = ty + 16 * s;
    int i = ti + yy, j = tj + tx;
    if (!INT && (i >= n || j >= n)) continue;
    size_t idx = base + (size_t)i * n + j;
    int pr = yy + 3, pc = tx + 3;
    psi_out[idx] = bufD[pr * 39 + pc];
    float qv = 0.f;
    if (INT || (i >= 1 && i < n - 1 && j >= 1 && j < n - 1)) {
      float z1v = bufA[(yy + 2) * 37 + tx + 2];
      int r2 = yy + 1, c2 = tx + 1;
      float z2v = bufC[r2 * 35 + c2];
      float z4 = (bufC[r2 * 35 + c2 - 1] + bufC[r2 * 35 + c2 + 1] +
                  bufC[(r2 - 1) * 35 + c2] + bufC[(r2 + 1) * 35 + c2]) * INV_DX2
                 - z2v * CENTER;
      float Amm = bufD[(pr - 1) * 39 + pc - 1], Am0 = bufD[(pr - 1) * 39 + pc],
            Amp = bufD[(pr - 1) * 39 + pc + 1];
      float A0m = bufD[pr * 39 + pc - 1], A0p = bufD[pr * 39 + pc + 1];
      float Apm = bufD[(pr + 1) * 39 + pc - 1], Ap0 = bufD[(pr + 1) * 39 + pc],
            App = bufD[(pr + 1) * 39 + pc + 1];
      int qr = yy + 4, qc = tx + 4;
      float J = (A0m - Am0) * bufB[(qr - 1) * 41 + qc - 1]
              + (Amm + A0m - Amp - A0p) * bufB[(qr - 1) * 41 + qc]
              + (Am0 - A0p) * bufB[(qr - 1) * 41 + qc + 1]
              + (Apm + Ap0 - Amm - Am0) * bufB[qr * 41 + qc - 1]
              + (Am0 + Amp - Ap0 - App) * bufB[qr * 41 + qc + 1]
              + (Ap0 - A0m) * bufB[(qr + 1) * 41 + qc - 1]
              + (A0p + App - A0m - Apm) * bufB[(qr + 1) * 41 + qc]
              + (A0p - Ap0) * bufB[(qr + 1) * 41 + qc + 1];
      J *= INV12S;
      float ct = CT[(size_t)i * n + j];
      qv = -J - 1e-6f * z1v + 1e-8f * z2v - 2e-11f * z4 + ct - 256.0f * (A0p - A0m);
    }
    qf_out[idx] = qv;
  }
}

__global__ __launch_bounds__(NT) void mega_k(
    const float* __restrict__ psi, const float* __restrict__ Qg,
    const float* __restrict__ q1g, const float* __restrict__ CT,
    float* __restrict__ psi_out, float* __restrict__ qf_out) {
  __shared__ float bufA[42 * 43];
  __shared__ float bufB[40 * 41];
  __shared__ float bufC[40 * 41];
  __shared__ float bufD[38 * 39];
  int bx = blockIdx.x, by = blockIdx.y;
  int ti = by * 32, tj = bx * 32;
  int c0i = 16 * by - 3, c0j = 16 * bx - 3;
  size_t base = (size_t)blockIdx.z * (N0 * N0);
  const float* q1 = q1g + (size_t)blockIdx.z * (N1 * N1);
  int lid = threadIdx.y * 32 + threadIdx.x;
  bool inter = (bx >= 1 && bx <= 14 && by >= 1 && by <= 14);
  if (inter)
    mega_body<true>(psi + base, Qg + base, q1, CT, psi_out, qf_out,
                    ti, tj, c0i, c0j, base, lid, bufA, bufB, bufC, bufD);
  else
    mega_body<false>(psi + base, Qg + base, q1, CT, psi_out, qf_out,
                     ti, tj, c0i, c0j, base, lid, bufA, bufB, bufC, bufD);
}

extern "C" void kernel_launch(void* const* d_in, const int* in_sizes, int n_in,
                              void* d_out, int out_size, void* d_ws, size_t ws_size,
                              hipStream_t stream) {
  const float* PSIG = (const float*)d_in[1];
  const float* Q    = (const float*)d_in[2];
  const float* CT   = (const float*)d_in[3];

  float* ws = (float*)d_ws;
  size_t f0 = (size_t)NB * N0 * N0;
  size_t f1 = (size_t)NB * N1 * N1;
  float* pA  = ws;
  float* pB  = pA + f0;
  float* q1a = pB + f0;
  float* q1b = q1a + f1;

  dim3 blk(32, 16, 1), grd(17, 17, NB);

  drelaxR_k<<<grd, blk, 0, stream>>>(PSIG, Q, pA, q1a);      // cycle-1 down
  vleg_k<<<grd, blk, 0, stream>>>(pA, Q, q1a, pB, q1b);      // c1 up + c2 down
  float* psi_out = (float*)d_out;
  float* qf_out  = psi_out + f0;
  mega_k<<<grd, blk, 0, stream>>>(pB, Q, q1b, CT, psi_out, qf_out);  // c2 up + flux
}